// Round 6
// baseline (306.180 us; speedup 1.0000x reference)
//
#include <hip/hip_runtime.h>

// SpinConvSq2d via MFMA (bf16). Round 6: DIAGNOSTIC build — main kernel body
// wrapped in a runtime nrep loop (idempotent, deterministic) so the main
// dispatch exceeds the 42us ws-poison fills and surfaces in rocprof top-5
// with full counters. dur delta vs R5 also decomposes prep/main/overhead.
// Structure otherwise byte-identical to R5.

typedef __attribute__((ext_vector_type(8))) short short8;
typedef __attribute__((ext_vector_type(16))) float f32x16;
typedef __attribute__((ext_vector_type(4))) float float4v;

typedef __attribute__((address_space(3))) unsigned char lds_u8_t;
typedef const __attribute__((address_space(1))) unsigned char g_u8_t;

#define FEATT_BYTES (8u * 64u * 64u * 64u * 2u)   // 4 MB bf16 featT (pre-swizzled)
#define BT_OFFSET   FEATT_BYTES                    // weight blob: 64000*2 B

#define MFMA32(A, B, C) __builtin_amdgcn_mfma_f32_32x32x16_bf16(A, B, C, 0, 0, 0)

__device__ __forceinline__ unsigned short f2bf(float f) {
    unsigned int u = __float_as_uint(f);
    return (unsigned short)((u + 0x7FFFu + ((u >> 16) & 1u)) >> 16);  // RNE
}

// ---------------- prep: featT (pre-swizzled bf16) + weight blob ----------------
__global__ __launch_bounds__(256) void prep_kernel(
    const float* __restrict__ feat,
    const float* __restrict__ W000, const float* __restrict__ W110,
    const float* __restrict__ W011, const float* __restrict__ W101,
    const float* __restrict__ W111,
    unsigned char* __restrict__ ws)
{
    int tid = threadIdx.x;
    int b = blockIdx.x;
    if (b < 512) {
        __shared__ float sf[64][68];
        size_t base = (size_t)b * 4096;       // floats
        #pragma unroll
        for (int i = 0; i < 4; ++i) {
            int e = tid + i * 256;            // float4 index 0..1023
            float4v v = *(const float4v*)(feat + base + (size_t)e * 4);
            int px = e >> 4;
            int c  = (e & 15) * 4;
            sf[px][c + 0] = v[0]; sf[px][c + 1] = v[1];
            sf[px][c + 2] = v[2]; sf[px][c + 3] = v[3];
        }
        __syncthreads();
        unsigned short* dst = (unsigned short*)ws + base;   // shorts
        #pragma unroll
        for (int i = 0; i < 2; ++i) {
            int q = tid + i * 256;            // 0..511: px*8 + s
            int px = q >> 3, s = q & 7;
            int y7 = px & 7;
            short8 o;
            #pragma unroll
            for (int j = 0; j < 8; ++j) {
                int chp = s * 8 + j;
                int c = (chp < 16) ? chp : (16 + 3 * ((chp - 16) & 15) + ((chp - 16) >> 4));
                o[j] = (short)f2bf(sf[px][c]);
            }
            *(short8*)(dst + px * 64 + ((s ^ y7) << 3)) = o;
        }
    } else {
        int t = (b - 512) * 256 + tid;        // 0..4095, need <4000
        if (t >= 4000) return;
        int a = t / 160, colv = t - a * 160;
        int arr = colv >> 5, w = colv & 31;
        const float* Wp = (arr == 0) ? W000 : (arr == 1) ? W011
                        : (arr == 2) ? W110 : (arr == 3) ? W101 : W111;
        unsigned short tmp[16];
        #pragma unroll
        for (int k = 0; k < 16; ++k) tmp[k] = f2bf(Wp[a * 512 + k * 32 + w]);
        unsigned short* d = (unsigned short*)(ws + BT_OFFSET) + (size_t)t * 16;
        *(short8*)(d)     = *(short8*)(tmp);
        *(short8*)(d + 8) = *(short8*)(tmp + 8);
    }
}

// ---------------- main MFMA kernel (nrep diagnostic loop) ----------------
__global__ __launch_bounds__(256, 2) void spinconv_mfma_kernel(
    const unsigned char* __restrict__ featT8,
    const unsigned char* __restrict__ bt,
    const float* __restrict__ spin,
    float* __restrict__ out,
    int nrep)
{
    const float SH0f   = 0.28209479177387814f;
    const float CG110f = 0.5773502691896258f;
    const float CG111f = 0.7071067811865476f;
    const float A0f    = 0.035355339059327376f;
    const float A1f    = 0.028867513459481287f;

    __shared__ __align__(16) unsigned char fl[5 * 64 * 128];  // 40 KB swizzled feat tile
    __shared__ float sbuf[2][16][64];                         // 8 KB: S011 handoff A->B
    __shared__ float s_lds[192];                              // SH1*spin for 64 pixels

    int tid = threadIdx.x;
    int bid = blockIdx.x;          // n*64 + x
    int x = bid & 63;

    int lane = tid & 63;
    int wv4 = tid >> 6;            // 0..3
    int pair = wv4 >> 1;
    int role = wv4 & 1;
    int col = lane & 31;
    int khalf = lane >> 5;
    int yb = pair << 5;
    int p0 = bid << 6;

    const unsigned char* bbase = bt + col * 32 + khalf * 16;

    for (int rep = 0; rep < nrep; ++rep) {
        __syncthreads();           // fl/sbuf reuse safe across reps

        // ---- async stage: 40 groups x 1KB ----
        #pragma unroll
        for (int i = 0; i < 10; ++i) {
            int g = wv4 * 10 + i;
            int dx = g >> 3;
            int X = (x + dx + 62) & 63;
            const unsigned char* src = featT8
                + ((size_t)(bid - x + X) * 64) * 128
                + (((g & 7) << 6) + lane) * 16;
            __builtin_amdgcn_global_load_lds((g_u8_t*)src, (lds_u8_t*)(fl + g * 1024), 16, 0, 0);
        }
        if (tid < 192) {
            s_lds[tid] = 0.4886025119029199f * spin[(size_t)bid * 192 + tid];
        }
        __syncthreads();

        f32x16 zz;
        #pragma unroll
        for (int i = 0; i < 16; ++i) zz[i] = 0.f;

        if (role == 0) {
            f32x16 aS000 = zz, aS011 = zz, aV0 = zz, aV1 = zz, aV2 = zz;
            short8 Bc0, Bc1, Bc2, Bn0, Bn1, Bn2;
            short8 Ax, Ac0, Ac1, Ac2, Nx, Nc0, Nc1, Nc2;

            auto loadB = [&](int a, short8& b0, short8& b1, short8& b2) {
                const unsigned char* p = bbase + a * 5120;
                b0 = *(const short8*)(p);            // W000
                b1 = *(const short8*)(p + 1024);     // W011
                b2 = *(const short8*)(p + 2048);     // W110
            };
            auto loadA = [&](int a, short8& ax, short8& c0, short8& c1, short8& c2) {
                int ix = a / 5;
                int iy = a - ix * 5;
                int yn = (yb + col + iy + 62) & 63;
                const unsigned char* ab = fl + ix * 8192 + yn * 128;
                int xr = (yn & 7) << 4;
                ax = *(const short8*)(ab + ((khalf << 4) ^ xr));
                c0 = *(const short8*)(ab + (((2 + khalf) << 4) ^ xr));
                c1 = *(const short8*)(ab + (((4 + khalf) << 4) ^ xr));
                c2 = *(const short8*)(ab + (((6 + khalf) << 4) ^ xr));
            };

            loadB(0, Bc0, Bc1, Bc2);
            loadA(0, Ax, Ac0, Ac1, Ac2);
            #pragma unroll
            for (int ap = 0; ap < 25; ap += 2) {
                if (ap + 1 < 25) { loadB(ap + 1, Bn0, Bn1, Bn2); loadA(ap + 1, Nx, Nc0, Nc1, Nc2); }
                aS000 = MFMA32(Ax,  Bc0, aS000);
                aS011 = MFMA32(Ax,  Bc1, aS011);
                aV0   = MFMA32(Ac0, Bc2, aV0);
                aV1   = MFMA32(Ac1, Bc2, aV1);
                aV2   = MFMA32(Ac2, Bc2, aV2);
                if (ap + 1 < 25) {
                    if (ap + 2 < 25) { loadB(ap + 2, Bc0, Bc1, Bc2); loadA(ap + 2, Ax, Ac0, Ac1, Ac2); }
                    aS000 = MFMA32(Nx,  Bn0, aS000);
                    aS011 = MFMA32(Nx,  Bn1, aS011);
                    aV0   = MFMA32(Nc0, Bn2, aV0);
                    aV1   = MFMA32(Nc1, Bn2, aV1);
                    aV2   = MFMA32(Nc2, Bn2, aV2);
                }
            }

            #pragma unroll
            for (int r = 0; r < 16; ++r) sbuf[pair][r][lane] = aS011[r];
            #pragma unroll
            for (int r = 0; r < 16; ++r) {
                int row = (r & 3) + ((r >> 2) << 3) + (khalf << 2);
                int y = yb + row;
                float s0 = s_lds[y * 3 + 0];
                float s1 = s_lds[y * 3 + 1];
                float s2 = s_lds[y * 3 + 2];
                float o0 = A0f * (SH0f * aS000[r]
                         + CG110f * (s0 * aV0[r] + s1 * aV1[r] + s2 * aV2[r]));
                out[(size_t)(p0 + y) * 128 + col] = o0;
            }
            __syncthreads();
        } else {
            f32x16 aT0 = zz, aT1 = zz, aT2 = zz, aU0 = zz, aU1 = zz, aU2 = zz;
            short8 Bc0, Bc1, Bn0, Bn1;
            short8 Ac0, Ac1, Ac2, Nc0, Nc1, Nc2;

            auto loadB = [&](int a, short8& b0, short8& b1) {
                const unsigned char* p = bbase + a * 5120;
                b0 = *(const short8*)(p + 3072);     // W101
                b1 = *(const short8*)(p + 4096);     // W111
            };
            auto loadA = [&](int a, short8& c0, short8& c1, short8& c2) {
                int ix = a / 5;
                int iy = a - ix * 5;
                int yn = (yb + col + iy + 62) & 63;
                const unsigned char* ab = fl + ix * 8192 + yn * 128;
                int xr = (yn & 7) << 4;
                c0 = *(const short8*)(ab + (((2 + khalf) << 4) ^ xr));
                c1 = *(const short8*)(ab + (((4 + khalf) << 4) ^ xr));
                c2 = *(const short8*)(ab + (((6 + khalf) << 4) ^ xr));
            };

            loadB(0, Bc0, Bc1);
            loadA(0, Ac0, Ac1, Ac2);
            #pragma unroll
            for (int ap = 0; ap < 25; ap += 2) {
                if (ap + 1 < 25) { loadB(ap + 1, Bn0, Bn1); loadA(ap + 1, Nc0, Nc1, Nc2); }
                aT0 = MFMA32(Ac0, Bc0, aT0);
                aU0 = MFMA32(Ac0, Bc1, aU0);
                aT1 = MFMA32(Ac1, Bc0, aT1);
                aU1 = MFMA32(Ac1, Bc1, aU1);
                aT2 = MFMA32(Ac2, Bc0, aT2);
                aU2 = MFMA32(Ac2, Bc1, aU2);
                if (ap + 1 < 25) {
                    if (ap + 2 < 25) { loadB(ap + 2, Bc0, Bc1); loadA(ap + 2, Ac0, Ac1, Ac2); }
                    aT0 = MFMA32(Nc0, Bn0, aT0);
                    aU0 = MFMA32(Nc0, Bn1, aU0);
                    aT1 = MFMA32(Nc1, Bn0, aT1);
                    aU1 = MFMA32(Nc1, Bn1, aU1);
                    aT2 = MFMA32(Nc2, Bn0, aT2);
                    aU2 = MFMA32(Nc2, Bn1, aU2);
                }
            }

            __syncthreads();   // wait for role A's sbuf (S011)

            #pragma unroll
            for (int r = 0; r < 16; ++r) {
                int row = (r & 3) + ((r >> 2) << 3) + (khalf << 2);
                int y = yb + row;
                float s0 = s_lds[y * 3 + 0];
                float s1 = s_lds[y * 3 + 1];
                float s2 = s_lds[y * 3 + 2];
                float S011 = sbuf[pair][r][lane];
                float T0 = aT0[r], T1 = aT1[r], T2 = aT2[r];
                float U0 = aU0[r], U1 = aU1[r], U2 = aU2[r];
                float c0 = U1 * s2 - U2 * s1;
                float c1 = U2 * s0 - U0 * s2;
                float c2 = U0 * s1 - U1 * s0;
                float* op = out + (size_t)(p0 + y) * 128;
                op[32 + 3 * col + 0] = A1f * (s0 * S011 + SH0f * T0 + CG111f * c0);
                op[32 + 3 * col + 1] = A1f * (s1 * S011 + SH0f * T1 + CG111f * c1);
                op[32 + 3 * col + 2] = A1f * (s2 * S011 + SH0f * T2 + CG111f * c2);
            }
        }
    }
}

extern "C" void kernel_launch(void* const* d_in, const int* in_sizes, int n_in,
                              void* d_out, int out_size, void* d_ws, size_t ws_size,
                              hipStream_t stream) {
    const float* feat = (const float*)d_in[0];
    const float* spin = (const float*)d_in[1];
    const float* W000 = (const float*)d_in[2];
    const float* W110 = (const float*)d_in[3];
    const float* W011 = (const float*)d_in[4];
    const float* W101 = (const float*)d_in[5];
    const float* W111 = (const float*)d_in[6];
    float* out = (float*)d_out;
    unsigned char* ws = (unsigned char*)d_ws;

    hipLaunchKernelGGL(prep_kernel, dim3(528), dim3(256), 0, stream,
                       feat, W000, W110, W011, W101, W111, ws);
    hipLaunchKernelGGL(spinconv_mfma_kernel, dim3(512), dim3(256), 0, stream,
                       ws, ws + BT_OFFSET, spin, out, 6);
}

// Round 7
// 26.064 us; speedup vs baseline: 11.7474x; 11.7474x over previous
//
#include <hip/hip_runtime.h>

// SpinConvSq2d via MFMA (bf16). Round 7:
//  - LDS tile transposed to [slot][y] -> A-fragment ds_read_b128 is linear
//    across lanes (conflict-free; R6 diagnostic measured 4-way conflicts in
//    the old [y][slot]+XOR layout: 717K conflict-cycles/pass).
//  - featT re-laid-out [column][slot][y] so global_load_lds stays linear.
//  - XCD-aware block remap: bid=(b&7)*64+(b>>3) gives each XCD 64 consecutive
//    columns (one n-slice, 512KB featT) -> private-L2 resident.
//  - __launch_bounds__(256,3): 3 blocks/CU (was 2).
// Math/factorization identical to R3-R6 (refchecked, absmax 0.0156):
//   S000,S011 = x0 x {W000,W011}; V,T,U[i] = x1_i x {W110,W101,W111}
//   out0   = A0*(SH0*S000 + CG110*dot(s,V))
//   out1_i = A1*(s_i*S011 + SH0*T_i + CG111*cross(U,s)_i),  s = SH1*spin

typedef __attribute__((ext_vector_type(8))) short short8;
typedef __attribute__((ext_vector_type(16))) float f32x16;
typedef __attribute__((ext_vector_type(4))) float float4v;

typedef __attribute__((address_space(3))) unsigned char lds_u8_t;
typedef const __attribute__((address_space(1))) unsigned char g_u8_t;

#define FEATT_BYTES (8u * 64u * 64u * 64u * 2u)   // 4 MB bf16 featT
#define BT_OFFSET   FEATT_BYTES                    // weight blob: 64000*2 B

#define MFMA32(A, B, C) __builtin_amdgcn_mfma_f32_32x32x16_bf16(A, B, C, 0, 0, 0)

__device__ __forceinline__ unsigned short f2bf(float f) {
    unsigned int u = __float_as_uint(f);
    return (unsigned short)((u + 0x7FFFu + ((u >> 16) & 1u)) >> 16);  // RNE
}

// ---------------- prep: featT [col][slot][y] bf16 + weight blob ----------------
// Column = (n*64+X): 8 slots x 64 y x 16B = 8192 B. Slot s holds reordered
// channels 8s..8s+7: chp<16 -> x0[chp], else x1 comp (chp-16)>>4 mul (chp-16)&15.
__global__ __launch_bounds__(256) void prep_kernel(
    const float* __restrict__ feat,
    const float* __restrict__ W000, const float* __restrict__ W110,
    const float* __restrict__ W011, const float* __restrict__ W101,
    const float* __restrict__ W111,
    unsigned char* __restrict__ ws)
{
    int tid = threadIdx.x;
    int b = blockIdx.x;
    if (b < 512) {
        __shared__ float sf[64][68];          // 68-pad spreads banks
        size_t base = (size_t)b * 4096;       // floats (= shorts per column, 4096)
        #pragma unroll
        for (int i = 0; i < 4; ++i) {
            int e = tid + i * 256;            // float4 index 0..1023
            float4v v = *(const float4v*)(feat + base + (size_t)e * 4);
            int px = e >> 4;
            int c  = (e & 15) * 4;
            sf[px][c + 0] = v[0]; sf[px][c + 1] = v[1];
            sf[px][c + 2] = v[2]; sf[px][c + 3] = v[3];
        }
        __syncthreads();
        unsigned short* dst = (unsigned short*)ws + base;
        #pragma unroll
        for (int i = 0; i < 2; ++i) {
            int t = tid + i * 256;            // 0..511: s*64 + px (s slow)
            int s = t >> 6, px = t & 63;
            short8 o;
            #pragma unroll
            for (int j = 0; j < 8; ++j) {
                int chp = s * 8 + j;
                int c = (chp < 16) ? chp : (16 + 3 * ((chp - 16) & 15) + ((chp - 16) >> 4));
                o[j] = (short)f2bf(sf[px][c]);
            }
            *(short8*)(dst + s * 512 + px * 8) = o;   // [slot][y] within column
        }
    } else {
        int t = (b - 512) * 256 + tid;        // 0..4095, need <4000
        if (t >= 4000) return;
        int a = t / 160, colv = t - a * 160;
        int arr = colv >> 5, w = colv & 31;
        const float* Wp = (arr == 0) ? W000 : (arr == 1) ? W011
                        : (arr == 2) ? W110 : (arr == 3) ? W101 : W111;
        unsigned short tmp[16];
        #pragma unroll
        for (int k = 0; k < 16; ++k) tmp[k] = f2bf(Wp[a * 512 + k * 32 + w]);
        unsigned short* d = (unsigned short*)(ws + BT_OFFSET) + (size_t)t * 16;
        *(short8*)(d)     = *(short8*)(tmp);
        *(short8*)(d + 8) = *(short8*)(tmp + 8);
    }
}

// ---------------- main MFMA kernel ----------------
__global__ __launch_bounds__(256, 3) void spinconv_mfma_kernel(
    const unsigned char* __restrict__ featT8,
    const unsigned char* __restrict__ bt,
    const float* __restrict__ spin,
    float* __restrict__ out)
{
    const float SH0f   = 0.28209479177387814f;
    const float CG110f = 0.5773502691896258f;
    const float CG111f = 0.7071067811865476f;
    const float A0f    = 0.035355339059327376f;
    const float A1f    = 0.028867513459481287f;

    __shared__ __align__(16) unsigned char fl[5 * 8 * 64 * 16]; // 40 KB [dx][slot][y]
    __shared__ float sbuf[2][16][64];                           // 8 KB: S011 handoff
    __shared__ float s_lds[192];                                // SH1*spin

    int tid = threadIdx.x;
    // XCD-aware remap: consecutive logical columns on the same XCD.
    int b = blockIdx.x;
    int bid = ((b & 7) << 6) + (b >> 3);   // n*64 + x
    int x = bid & 63;

    int lane = tid & 63;
    int wv4 = tid >> 6;            // 0..3

    // ---- async stage: 40 groups x 1KB, fully linear both sides ----
    #pragma unroll
    for (int i = 0; i < 10; ++i) {
        int g = wv4 * 10 + i;                 // g = dx*8 + s
        int dx = g >> 3;
        int X = (x + dx + 62) & 63;
        const unsigned char* src = featT8
            + (size_t)(bid - x + X) * 8192 + (g & 7) * 1024 + lane * 16;
        __builtin_amdgcn_global_load_lds((g_u8_t*)src, (lds_u8_t*)(fl + g * 1024), 16, 0, 0);
    }
    if (tid < 192) {
        s_lds[tid] = 0.4886025119029199f * spin[(size_t)bid * 192 + tid];
    }
    __syncthreads();

    int pair = wv4 >> 1;           // pixel half: 0 -> y 0-31, 1 -> y 32-63
    int role = wv4 & 1;            // 0: S000,S011,V; 1: T,U
    int col = lane & 31;           // N-col (w) and A-row (pixel within tile)
    int khalf = lane >> 5;         // K-half select
    int yb = pair << 5;
    int p0 = bid << 6;

    const unsigned char* bbase = bt + col * 32 + khalf * 16;

    f32x16 zz;
    #pragma unroll
    for (int i = 0; i < 16; ++i) zz[i] = 0.f;

    if (role == 0) {
        f32x16 aS000 = zz, aS011 = zz, aV0 = zz, aV1 = zz, aV2 = zz;
        short8 Bc0, Bc1, Bc2, Bn0, Bn1, Bn2;
        short8 Ax, Ac0, Ac1, Ac2, Nx, Nc0, Nc1, Nc2;

        auto loadB = [&](int a, short8& b0, short8& b1, short8& b2) {
            const unsigned char* p = bbase + a * 5120;
            b0 = *(const short8*)(p);            // W000
            b1 = *(const short8*)(p + 1024);     // W011
            b2 = *(const short8*)(p + 2048);     // W110
        };
        auto loadA = [&](int a, short8& ax, short8& c0, short8& c1, short8& c2) {
            int ix = a / 5;
            int iy = a - ix * 5;
            int yn = (yb + col + iy + 62) & 63;
            const unsigned char* ab = fl + ix * 8192 + yn * 16;   // [slot][y]
            ax = *(const short8*)(ab + (0 + khalf) * 1024);
            c0 = *(const short8*)(ab + (2 + khalf) * 1024);
            c1 = *(const short8*)(ab + (4 + khalf) * 1024);
            c2 = *(const short8*)(ab + (6 + khalf) * 1024);
        };

        loadB(0, Bc0, Bc1, Bc2);
        loadA(0, Ax, Ac0, Ac1, Ac2);
        #pragma unroll
        for (int ap = 0; ap < 25; ap += 2) {
            if (ap + 1 < 25) { loadB(ap + 1, Bn0, Bn1, Bn2); loadA(ap + 1, Nx, Nc0, Nc1, Nc2); }
            aS000 = MFMA32(Ax,  Bc0, aS000);
            aS011 = MFMA32(Ax,  Bc1, aS011);
            aV0   = MFMA32(Ac0, Bc2, aV0);
            aV1   = MFMA32(Ac1, Bc2, aV1);
            aV2   = MFMA32(Ac2, Bc2, aV2);
            if (ap + 1 < 25) {
                if (ap + 2 < 25) { loadB(ap + 2, Bc0, Bc1, Bc2); loadA(ap + 2, Ax, Ac0, Ac1, Ac2); }
                aS000 = MFMA32(Nx,  Bn0, aS000);
                aS011 = MFMA32(Nx,  Bn1, aS011);
                aV0   = MFMA32(Nc0, Bn2, aV0);
                aV1   = MFMA32(Nc1, Bn2, aV1);
                aV2   = MFMA32(Nc2, Bn2, aV2);
            }
        }

        #pragma unroll
        for (int r = 0; r < 16; ++r) sbuf[pair][r][lane] = aS011[r];
        #pragma unroll
        for (int r = 0; r < 16; ++r) {
            int row = (r & 3) + ((r >> 2) << 3) + (khalf << 2);
            int y = yb + row;
            float s0 = s_lds[y * 3 + 0];
            float s1 = s_lds[y * 3 + 1];
            float s2 = s_lds[y * 3 + 2];
            float o0 = A0f * (SH0f * aS000[r]
                     + CG110f * (s0 * aV0[r] + s1 * aV1[r] + s2 * aV2[r]));
            out[(size_t)(p0 + y) * 128 + col] = o0;
        }
        __syncthreads();
    } else {
        f32x16 aT0 = zz, aT1 = zz, aT2 = zz, aU0 = zz, aU1 = zz, aU2 = zz;
        short8 Bc0, Bc1, Bn0, Bn1;
        short8 Ac0, Ac1, Ac2, Nc0, Nc1, Nc2;

        auto loadB = [&](int a, short8& b0, short8& b1) {
            const unsigned char* p = bbase + a * 5120;
            b0 = *(const short8*)(p + 3072);     // W101
            b1 = *(const short8*)(p + 4096);     // W111
        };
        auto loadA = [&](int a, short8& c0, short8& c1, short8& c2) {
            int ix = a / 5;
            int iy = a - ix * 5;
            int yn = (yb + col + iy + 62) & 63;
            const unsigned char* ab = fl + ix * 8192 + yn * 16;   // [slot][y]
            c0 = *(const short8*)(ab + (2 + khalf) * 1024);
            c1 = *(const short8*)(ab + (4 + khalf) * 1024);
            c2 = *(const short8*)(ab + (6 + khalf) * 1024);
        };

        loadB(0, Bc0, Bc1);
        loadA(0, Ac0, Ac1, Ac2);
        #pragma unroll
        for (int ap = 0; ap < 25; ap += 2) {
            if (ap + 1 < 25) { loadB(ap + 1, Bn0, Bn1); loadA(ap + 1, Nc0, Nc1, Nc2); }
            aT0 = MFMA32(Ac0, Bc0, aT0);
            aU0 = MFMA32(Ac0, Bc1, aU0);
            aT1 = MFMA32(Ac1, Bc0, aT1);
            aU1 = MFMA32(Ac1, Bc1, aU1);
            aT2 = MFMA32(Ac2, Bc0, aT2);
            aU2 = MFMA32(Ac2, Bc1, aU2);
            if (ap + 1 < 25) {
                if (ap + 2 < 25) { loadB(ap + 2, Bc0, Bc1); loadA(ap + 2, Ac0, Ac1, Ac2); }
                aT0 = MFMA32(Nc0, Bn0, aT0);
                aU0 = MFMA32(Nc0, Bn1, aU0);
                aT1 = MFMA32(Nc1, Bn0, aT1);
                aU1 = MFMA32(Nc1, Bn1, aU1);
                aT2 = MFMA32(Nc2, Bn0, aT2);
                aU2 = MFMA32(Nc2, Bn1, aU2);
            }
        }

        __syncthreads();   // wait for role A's sbuf (S011)

        #pragma unroll
        for (int r = 0; r < 16; ++r) {
            int row = (r & 3) + ((r >> 2) << 3) + (khalf << 2);
            int y = yb + row;
            float s0 = s_lds[y * 3 + 0];
            float s1 = s_lds[y * 3 + 1];
            float s2 = s_lds[y * 3 + 2];
            float S011 = sbuf[pair][r][lane];
            float T0 = aT0[r], T1 = aT1[r], T2 = aT2[r];
            float U0 = aU0[r], U1 = aU1[r], U2 = aU2[r];
            float c0 = U1 * s2 - U2 * s1;
            float c1 = U2 * s0 - U0 * s2;
            float c2 = U0 * s1 - U1 * s0;
            float* op = out + (size_t)(p0 + y) * 128;
            op[32 + 3 * col + 0] = A1f * (s0 * S011 + SH0f * T0 + CG111f * c0);
            op[32 + 3 * col + 1] = A1f * (s1 * S011 + SH0f * T1 + CG111f * c1);
            op[32 + 3 * col + 2] = A1f * (s2 * S011 + SH0f * T2 + CG111f * c2);
        }
    }
}

extern "C" void kernel_launch(void* const* d_in, const int* in_sizes, int n_in,
                              void* d_out, int out_size, void* d_ws, size_t ws_size,
                              hipStream_t stream) {
    const float* feat = (const float*)d_in[0];
    const float* spin = (const float*)d_in[1];
    const float* W000 = (const float*)d_in[2];
    const float* W110 = (const float*)d_in[3];
    const float* W011 = (const float*)d_in[4];
    const float* W101 = (const float*)d_in[5];
    const float* W111 = (const float*)d_in[6];
    float* out = (float*)d_out;
    unsigned char* ws = (unsigned char*)d_ws;

    hipLaunchKernelGGL(prep_kernel, dim3(528), dim3(256), 0, stream,
                       feat, W000, W110, W011, W101, W111, ws);
    hipLaunchKernelGGL(spinconv_mfma_kernel, dim3(512), dim3(256), 0, stream,
                       ws, ws + BT_OFFSET, spin, out);
}

// Round 8
// 22.762 us; speedup vs baseline: 13.4512x; 1.1450x over previous
//
#include <hip/hip_runtime.h>

// SpinConvSq2d via MFMA (bf16). Round 8:
//  - Epilogue rewritten: results staged into LDS row buffer (reuses the dead
//    40KB feat tile after a barrier), then cooperatively stored as contiguous
//    float4 lines. Kills the 2.7x partial-sector write inflation + RMW fetch
//    measured in R6 (WRITE 46MB/pass vs 16.8MB logical).
//  - s_setprio(1) around MFMA clusters (role-diverse waves -> T5 regime).
//  - Everything else identical to R7 (linear [slot][y] LDS, XCD remap,
//    3 blocks/CU, async global_load_lds staging).
// Math/factorization identical to R3-R7 (refchecked, absmax 0.0156):
//   S000,S011 = x0 x {W000,W011}; V,T,U[i] = x1_i x {W110,W101,W111}
//   out0   = A0*(SH0*S000 + CG110*dot(s,V))
//   out1_i = A1*(s_i*S011 + SH0*T_i + CG111*cross(U,s)_i),  s = SH1*spin

typedef __attribute__((ext_vector_type(8))) short short8;
typedef __attribute__((ext_vector_type(16))) float f32x16;
typedef __attribute__((ext_vector_type(4))) float float4v;

typedef __attribute__((address_space(3))) unsigned char lds_u8_t;
typedef const __attribute__((address_space(1))) unsigned char g_u8_t;

#define FEATT_BYTES (8u * 64u * 64u * 64u * 2u)   // 4 MB bf16 featT
#define BT_OFFSET   FEATT_BYTES                    // weight blob: 64000*2 B

#define MFMA32(A, B, C) __builtin_amdgcn_mfma_f32_32x32x16_bf16(A, B, C, 0, 0, 0)

__device__ __forceinline__ unsigned short f2bf(float f) {
    unsigned int u = __float_as_uint(f);
    return (unsigned short)((u + 0x7FFFu + ((u >> 16) & 1u)) >> 16);  // RNE
}

// ---------------- prep: featT [col][slot][y] bf16 + weight blob ----------------
__global__ __launch_bounds__(256) void prep_kernel(
    const float* __restrict__ feat,
    const float* __restrict__ W000, const float* __restrict__ W110,
    const float* __restrict__ W011, const float* __restrict__ W101,
    const float* __restrict__ W111,
    unsigned char* __restrict__ ws)
{
    int tid = threadIdx.x;
    int b = blockIdx.x;
    if (b < 512) {
        __shared__ float sf[64][68];          // 68-pad spreads banks
        size_t base = (size_t)b * 4096;       // floats (= shorts per column)
        #pragma unroll
        for (int i = 0; i < 4; ++i) {
            int e = tid + i * 256;            // float4 index 0..1023
            float4v v = *(const float4v*)(feat + base + (size_t)e * 4);
            int px = e >> 4;
            int c  = (e & 15) * 4;
            sf[px][c + 0] = v[0]; sf[px][c + 1] = v[1];
            sf[px][c + 2] = v[2]; sf[px][c + 3] = v[3];
        }
        __syncthreads();
        unsigned short* dst = (unsigned short*)ws + base;
        #pragma unroll
        for (int i = 0; i < 2; ++i) {
            int t = tid + i * 256;            // 0..511: s*64 + px
            int s = t >> 6, px = t & 63;
            short8 o;
            #pragma unroll
            for (int j = 0; j < 8; ++j) {
                int chp = s * 8 + j;
                int c = (chp < 16) ? chp : (16 + 3 * ((chp - 16) & 15) + ((chp - 16) >> 4));
                o[j] = (short)f2bf(sf[px][c]);
            }
            *(short8*)(dst + s * 512 + px * 8) = o;   // [slot][y] within column
        }
    } else {
        int t = (b - 512) * 256 + tid;        // 0..4095, need <4000
        if (t >= 4000) return;
        int a = t / 160, colv = t - a * 160;
        int arr = colv >> 5, w = colv & 31;
        const float* Wp = (arr == 0) ? W000 : (arr == 1) ? W011
                        : (arr == 2) ? W110 : (arr == 3) ? W101 : W111;
        unsigned short tmp[16];
        #pragma unroll
        for (int k = 0; k < 16; ++k) tmp[k] = f2bf(Wp[a * 512 + k * 32 + w]);
        unsigned short* d = (unsigned short*)(ws + BT_OFFSET) + (size_t)t * 16;
        *(short8*)(d)     = *(short8*)(tmp);
        *(short8*)(d + 8) = *(short8*)(tmp + 8);
    }
}

// ---------------- main MFMA kernel ----------------
__global__ __launch_bounds__(256, 3) void spinconv_mfma_kernel(
    const unsigned char* __restrict__ featT8,
    const unsigned char* __restrict__ bt,
    const float* __restrict__ spin,
    float* __restrict__ out)
{
    const float SH0f   = 0.28209479177387814f;
    const float CG110f = 0.5773502691896258f;
    const float CG111f = 0.7071067811865476f;
    const float A0f    = 0.035355339059327376f;
    const float A1f    = 0.028867513459481287f;

    __shared__ __align__(16) unsigned char fl[5 * 8 * 64 * 16]; // 40 KB [dx][slot][y]; reused as rowbuf
    __shared__ float sbuf[2][16][64];                           // 8 KB: S011 handoff
    __shared__ float s_lds[192];                                // SH1*spin

    int tid = threadIdx.x;
    int b = blockIdx.x;
    int bid = ((b & 7) << 6) + (b >> 3);   // XCD-aware remap: n*64 + x
    int x = bid & 63;

    int lane = tid & 63;
    int wv4 = tid >> 6;            // 0..3

    // ---- async stage: 40 groups x 1KB, fully linear both sides ----
    #pragma unroll
    for (int i = 0; i < 10; ++i) {
        int g = wv4 * 10 + i;                 // g = dx*8 + s
        int dx = g >> 3;
        int X = (x + dx + 62) & 63;
        const unsigned char* src = featT8
            + (size_t)(bid - x + X) * 8192 + (g & 7) * 1024 + lane * 16;
        __builtin_amdgcn_global_load_lds((g_u8_t*)src, (lds_u8_t*)(fl + g * 1024), 16, 0, 0);
    }
    if (tid < 192) {
        s_lds[tid] = 0.4886025119029199f * spin[(size_t)bid * 192 + tid];
    }
    __syncthreads();

    int pair = wv4 >> 1;           // pixel half: 0 -> y 0-31, 1 -> y 32-63
    int role = wv4 & 1;            // 0: S000,S011,V; 1: T,U
    int col = lane & 31;           // N-col (w) and A-row (pixel within tile)
    int khalf = lane >> 5;         // K-half select
    int yb = pair << 5;
    int p0 = bid << 6;

    const unsigned char* bbase = bt + col * 32 + khalf * 16;
    float* rowbuf = (float*)fl;    // [64][128] floats after loops

    f32x16 zz;
    #pragma unroll
    for (int i = 0; i < 16; ++i) zz[i] = 0.f;

    // accumulators live per-role; epilogue values computed after barrier
    f32x16 aS000 = zz, aS011 = zz, aV0 = zz, aV1 = zz, aV2 = zz;   // role 0
    f32x16 aT0 = zz, aT1 = zz, aT2 = zz, aU0 = zz, aU1 = zz, aU2 = zz; // role 1

    if (role == 0) {
        short8 Bc0, Bc1, Bc2, Bn0, Bn1, Bn2;
        short8 Ax, Ac0, Ac1, Ac2, Nx, Nc0, Nc1, Nc2;

        auto loadB = [&](int a, short8& b0, short8& b1, short8& b2) {
            const unsigned char* p = bbase + a * 5120;
            b0 = *(const short8*)(p);            // W000
            b1 = *(const short8*)(p + 1024);     // W011
            b2 = *(const short8*)(p + 2048);     // W110
        };
        auto loadA = [&](int a, short8& ax, short8& c0, short8& c1, short8& c2) {
            int ix = a / 5;
            int iy = a - ix * 5;
            int yn = (yb + col + iy + 62) & 63;
            const unsigned char* ab = fl + ix * 8192 + yn * 16;   // [slot][y]
            ax = *(const short8*)(ab + (0 + khalf) * 1024);
            c0 = *(const short8*)(ab + (2 + khalf) * 1024);
            c1 = *(const short8*)(ab + (4 + khalf) * 1024);
            c2 = *(const short8*)(ab + (6 + khalf) * 1024);
        };

        loadB(0, Bc0, Bc1, Bc2);
        loadA(0, Ax, Ac0, Ac1, Ac2);
        #pragma unroll
        for (int ap = 0; ap < 25; ap += 2) {
            if (ap + 1 < 25) { loadB(ap + 1, Bn0, Bn1, Bn2); loadA(ap + 1, Nx, Nc0, Nc1, Nc2); }
            __builtin_amdgcn_s_setprio(1);
            aS000 = MFMA32(Ax,  Bc0, aS000);
            aS011 = MFMA32(Ax,  Bc1, aS011);
            aV0   = MFMA32(Ac0, Bc2, aV0);
            aV1   = MFMA32(Ac1, Bc2, aV1);
            aV2   = MFMA32(Ac2, Bc2, aV2);
            __builtin_amdgcn_s_setprio(0);
            if (ap + 1 < 25) {
                if (ap + 2 < 25) { loadB(ap + 2, Bc0, Bc1, Bc2); loadA(ap + 2, Ax, Ac0, Ac1, Ac2); }
                __builtin_amdgcn_s_setprio(1);
                aS000 = MFMA32(Nx,  Bn0, aS000);
                aS011 = MFMA32(Nx,  Bn1, aS011);
                aV0   = MFMA32(Nc0, Bn2, aV0);
                aV1   = MFMA32(Nc1, Bn2, aV1);
                aV2   = MFMA32(Nc2, Bn2, aV2);
                __builtin_amdgcn_s_setprio(0);
            }
        }
        // hand S011 to role B (sbuf is a separate buffer; safe pre-barrier)
        #pragma unroll
        for (int r = 0; r < 16; ++r) sbuf[pair][r][lane] = aS011[r];
    } else {
        short8 Bc0, Bc1, Bn0, Bn1;
        short8 Ac0, Ac1, Ac2, Nc0, Nc1, Nc2;

        auto loadB = [&](int a, short8& b0, short8& b1) {
            const unsigned char* p = bbase + a * 5120;
            b0 = *(const short8*)(p + 3072);     // W101
            b1 = *(const short8*)(p + 4096);     // W111
        };
        auto loadA = [&](int a, short8& c0, short8& c1, short8& c2) {
            int ix = a / 5;
            int iy = a - ix * 5;
            int yn = (yb + col + iy + 62) & 63;
            const unsigned char* ab = fl + ix * 8192 + yn * 16;   // [slot][y]
            c0 = *(const short8*)(ab + (2 + khalf) * 1024);
            c1 = *(const short8*)(ab + (4 + khalf) * 1024);
            c2 = *(const short8*)(ab + (6 + khalf) * 1024);
        };

        loadB(0, Bc0, Bc1);
        loadA(0, Ac0, Ac1, Ac2);
        #pragma unroll
        for (int ap = 0; ap < 25; ap += 2) {
            if (ap + 1 < 25) { loadB(ap + 1, Bn0, Bn1); loadA(ap + 1, Nc0, Nc1, Nc2); }
            __builtin_amdgcn_s_setprio(1);
            aT0 = MFMA32(Ac0, Bc0, aT0);
            aU0 = MFMA32(Ac0, Bc1, aU0);
            aT1 = MFMA32(Ac1, Bc0, aT1);
            aU1 = MFMA32(Ac1, Bc1, aU1);
            aT2 = MFMA32(Ac2, Bc0, aT2);
            aU2 = MFMA32(Ac2, Bc1, aU2);
            __builtin_amdgcn_s_setprio(0);
            if (ap + 1 < 25) {
                if (ap + 2 < 25) { loadB(ap + 2, Bc0, Bc1); loadA(ap + 2, Ac0, Ac1, Ac2); }
                __builtin_amdgcn_s_setprio(1);
                aT0 = MFMA32(Nc0, Bn0, aT0);
                aU0 = MFMA32(Nc0, Bn1, aU0);
                aT1 = MFMA32(Nc1, Bn0, aT1);
                aU1 = MFMA32(Nc1, Bn1, aU1);
                aT2 = MFMA32(Nc2, Bn0, aT2);
                aU2 = MFMA32(Nc2, Bn1, aU2);
                __builtin_amdgcn_s_setprio(0);
            }
        }
    }

    __syncthreads();   // all tap loops done: fl dead, sbuf ready -> reuse fl as rowbuf

    // ---- deposit results into LDS row buffer (C/D row = (r&3)+8*(r>>2)+4*khalf) ----
    if (role == 0) {
        #pragma unroll
        for (int r = 0; r < 16; ++r) {
            int row = (r & 3) + ((r >> 2) << 3) + (khalf << 2);
            int y = yb + row;
            float s0 = s_lds[y * 3 + 0];
            float s1 = s_lds[y * 3 + 1];
            float s2 = s_lds[y * 3 + 2];
            float o0 = A0f * (SH0f * aS000[r]
                     + CG110f * (s0 * aV0[r] + s1 * aV1[r] + s2 * aV2[r]));
            rowbuf[y * 128 + col] = o0;
        }
    } else {
        #pragma unroll
        for (int r = 0; r < 16; ++r) {
            int row = (r & 3) + ((r >> 2) << 3) + (khalf << 2);
            int y = yb + row;
            float s0 = s_lds[y * 3 + 0];
            float s1 = s_lds[y * 3 + 1];
            float s2 = s_lds[y * 3 + 2];
            float S011 = sbuf[pair][r][lane];
            float T0 = aT0[r], T1 = aT1[r], T2 = aT2[r];
            float U0 = aU0[r], U1 = aU1[r], U2 = aU2[r];
            float c0 = U1 * s2 - U2 * s1;
            float c1 = U2 * s0 - U0 * s2;
            float c2 = U0 * s1 - U1 * s0;
            float* rp = rowbuf + y * 128 + 32 + 3 * col;
            rp[0] = A1f * (s0 * S011 + SH0f * T0 + CG111f * c0);
            rp[1] = A1f * (s1 * S011 + SH0f * T1 + CG111f * c1);
            rp[2] = A1f * (s2 * S011 + SH0f * T2 + CG111f * c2);
        }
    }

    __syncthreads();

    // ---- cooperative contiguous store: 64 rows x 512B = 32KB, float4 lanes ----
    float* ob = out + (size_t)p0 * 128;
    #pragma unroll
    for (int i = 0; i < 8; ++i) {
        int e = (tid + (i << 8)) << 2;        // float offset, 16B-aligned
        *(float4v*)(ob + e) = *(const float4v*)(rowbuf + e);
    }
}

extern "C" void kernel_launch(void* const* d_in, const int* in_sizes, int n_in,
                              void* d_out, int out_size, void* d_ws, size_t ws_size,
                              hipStream_t stream) {
    const float* feat = (const float*)d_in[0];
    const float* spin = (const float*)d_in[1];
    const float* W000 = (const float*)d_in[2];
    const float* W110 = (const float*)d_in[3];
    const float* W011 = (const float*)d_in[4];
    const float* W101 = (const float*)d_in[5];
    const float* W111 = (const float*)d_in[6];
    float* out = (float*)d_out;
    unsigned char* ws = (unsigned char*)d_ws;

    hipLaunchKernelGGL(prep_kernel, dim3(528), dim3(256), 0, stream,
                       feat, W000, W110, W011, W101, W111, ws);
    hipLaunchKernelGGL(spinconv_mfma_kernel, dim3(512), dim3(256), 0, stream,
                       ws, ws + BT_OFFSET, spin, out);
}